// Round 5
// baseline (142.654 us; speedup 1.0000x reference)
//
#include <hip/hip_runtime.h>
#include <hip/hip_bf16.h>

typedef __attribute__((ext_vector_type(4))) float  f32x4;
typedef __attribute__((ext_vector_type(8))) short  short8;

#define EMBED 4096
#define LR    512
#define KSEL  128
#define BATCH 8192
#define NSLICE 8
#define KSLICE 512

__device__ __forceinline__ short f2bf(float x) {
  union { float f; unsigned u; } c; c.f = x;
  unsigned r = c.u + 0x7FFFu + ((c.u >> 16) & 1u);  // RNE
  return (short)(r >> 16);
}
__device__ __forceinline__ float bf2f(short s) {
  union { unsigned u; float f; } c; c.u = ((unsigned)(unsigned short)s) << 16;
  return c.f;
}
__device__ __forceinline__ void storept(float* p, float v) { *p = v; }
__device__ __forceinline__ void storept(short* p, float v) { *p = f2bf(v); }
__device__ __forceinline__ void loadpart(const float* p, f32x4& a, f32x4& b) {
  a += *(const f32x4*)p; b += *(const f32x4*)(p + 4);
}
__device__ __forceinline__ void loadpart(const short* p, f32x4& a, f32x4& b) {
  short8 v = *(const short8*)p;
  #pragma unroll
  for (int j = 0; j < 4; ++j) { a[j] += bf2f(v[j]); b[j] += bf2f(v[4 + j]); }
}

// K0: gather selected columns of W, emit two bf16 MFMA-packed layouts.
// Wp : [e/8][128 cols][8]  (B-operand for GEMM1: kk-dim = embed)
// Wtp: [c/8][4096 e ][8]  (B-operand for GEMM2: kk-dim = sel index)
__global__ __launch_bounds__(256) void pack_w_kernel(
    const float* __restrict__ W, const int* __restrict__ sel,
    short* __restrict__ Wp, short* __restrict__ Wtp) {
  int idx = blockIdx.x * 256 + threadIdx.x;
  int e = idx >> 7;
  int c = idx & 127;
  int r = sel[c];
  short v = f2bf(W[e * LR + r]);
  Wp [(((e >> 3) << 7) + c) * 8 + (e & 7)] = v;
  Wtp[(((c >> 3) << 12) + e) * 8 + (c & 7)] = v;
}

// K1a: Tpart[slice] = (src-base)[:, k0:k0+512) @ Wsel[k0:k0+512), :]
// Grid 512 = 64 rowgroups x 8 kslices; block 512 thr = 8 independent waves.
// Wave = 16 rows x 128 cols x K=512: 16 STRAIGHT-LINE ksteps — no loop,
// no barrier, no LDS. A-frags direct from global (f32x4 pairs), B-frags
// streamed from L2-resident Wp (never held in regs), packed cvt_pk bf16.
template<typename PT>
__global__ __launch_bounds__(512, 4) void gemm1a_kernel(
    const float* __restrict__ base, const float* __restrict__ src,
    const short* __restrict__ Wp, PT* __restrict__ Tpart) {
  const int t  = threadIdx.x;
  const int w  = t >> 6, l = t & 63;
  const int lr = l & 15, lg = l >> 4;
  const int rg = blockIdx.x & 63, slice = blockIdx.x >> 6;
  const int row0 = rg * 128 + w * 16;
  const int k0 = slice * KSLICE;

  const float* bp = base + (size_t)(row0 + lr) * EMBED + k0 + lg * 8;
  const float* sp = src  + (size_t)(row0 + lr) * EMBED + k0 + lg * 8;
  // B frag (short8) index: (k0/8 + ks*4 + lg)*128 + c*16 + lr
  const short8* wq = (const short8*)Wp + ((k0 >> 3) + lg) * 128 + lr;

  f32x4 acc[8];
  #pragma unroll
  for (int c = 0; c < 8; ++c) acc[c] = (f32x4){0.f, 0.f, 0.f, 0.f};

  #pragma unroll
  for (int ks = 0; ks < 16; ++ks) {
    f32x4 b0 = *(const f32x4*)(bp + ks * 32);
    f32x4 b1 = *(const f32x4*)(bp + ks * 32 + 4);
    f32x4 s0 = *(const f32x4*)(sp + ks * 32);
    f32x4 s1 = *(const f32x4*)(sp + ks * 32 + 4);
    union { short8 v; __hip_bfloat162 h[4]; } ua;
    ua.h[0] = __float22bfloat162_rn(make_float2(s0[0] - b0[0], s0[1] - b0[1]));
    ua.h[1] = __float22bfloat162_rn(make_float2(s0[2] - b0[2], s0[3] - b0[3]));
    ua.h[2] = __float22bfloat162_rn(make_float2(s1[0] - b1[0], s1[1] - b1[1]));
    ua.h[3] = __float22bfloat162_rn(make_float2(s1[2] - b1[2], s1[3] - b1[3]));
    #pragma unroll
    for (int c = 0; c < 8; ++c) {
      short8 bf = wq[ks * 512 + c * 16];
      acc[c] = __builtin_amdgcn_mfma_f32_16x16x32_bf16(ua.v, bf, acc[c], 0, 0, 0);
    }
  }

  // lane holds Tpart[slice][row0 + 4lg + r][c*16 + lr]
  PT* o = Tpart + ((size_t)slice * BATCH + row0 + lg * 4) * KSEL + lr;
  #pragma unroll
  for (int c = 0; c < 8; ++c)
    #pragma unroll
    for (int r = 0; r < 4; ++r)
      storept(o + (size_t)r * KSEL + c * 16, acc[c][r]);
}

// K1b: Tp (packed bf16 [kk/8][8192][8]) = sum of 8 Tpart slices
template<typename PT>
__global__ __launch_bounds__(512) void reduce_kernel(
    const PT* __restrict__ Tpart, short* __restrict__ Tp) {
  const int tid = blockIdx.x * 512 + threadIdx.x;   // 0..131071
  const int kkg = tid & 15, row = tid >> 4;
  f32x4 s0 = {0.f, 0.f, 0.f, 0.f}, s1 = {0.f, 0.f, 0.f, 0.f};
  #pragma unroll
  for (int s = 0; s < NSLICE; ++s)
    loadpart(Tpart + ((size_t)s * BATCH + row) * KSEL + kkg * 8, s0, s1);
  short8 o;
  #pragma unroll
  for (int j = 0; j < 4; ++j) { o[j] = f2bf(s0[j]); o[4 + j] = f2bf(s1[j]); }
  *(short8*)(Tp + ((size_t)kkg * BATCH + row) * 8) = o;
}

// K2: out = base + T @ Wsel^T. Block: 64 rows x 256 cols, 4 waves.
__global__ __launch_bounds__(256) void gemm2_kernel(
    const float* __restrict__ base, const short* __restrict__ Tp,
    const short* __restrict__ Wtp, float* __restrict__ out) {
  const int t  = threadIdx.x;
  const int w  = t >> 6, l = t & 63;
  const int lr = l & 15, lg = l >> 4;
  const int mt = blockIdx.x >> 4, nt = blockIdx.x & 15;
  const int row0 = mt * 64;
  const int col0 = nt * 256 + w * 64;

  short8 afr[4][4];
  #pragma unroll
  for (int m = 0; m < 4; ++m)
    #pragma unroll
    for (int ks = 0; ks < 4; ++ks)
      afr[m][ks] = *(const short8*)(Tp + (size_t)(((ks * 4 + lg) << 13) + row0 + m * 16 + lr) * 8);

  f32x4 acc[4][4];
  #pragma unroll
  for (int m = 0; m < 4; ++m)
    #pragma unroll
    for (int nf = 0; nf < 4; ++nf) acc[m][nf] = (f32x4){0.f, 0.f, 0.f, 0.f};

  #pragma unroll
  for (int nf = 0; nf < 4; ++nf) {
    short8 bfr[4];
    #pragma unroll
    for (int ks = 0; ks < 4; ++ks)
      bfr[ks] = *(const short8*)(Wtp + (size_t)(((ks * 4 + lg) << 12) + col0 + nf * 16 + lr) * 8);
    #pragma unroll
    for (int m = 0; m < 4; ++m)
      #pragma unroll
      for (int ks = 0; ks < 4; ++ks)
        acc[m][nf] = __builtin_amdgcn_mfma_f32_16x16x32_bf16(afr[m][ks], bfr[ks], acc[m][nf], 0, 0, 0);
  }

  #pragma unroll
  for (int m = 0; m < 4; ++m)
    #pragma unroll
    for (int r = 0; r < 4; ++r) {
      const size_t row = row0 + m * 16 + lg * 4 + r;
      #pragma unroll
      for (int nf = 0; nf < 4; ++nf) {
        const size_t o = row * EMBED + col0 + nf * 16 + lr;
        out[o] = base[o] + acc[m][nf][r];
      }
    }
}

extern "C" void kernel_launch(void* const* d_in, const int* in_sizes, int n_in,
                              void* d_out, int out_size, void* d_ws, size_t ws_size,
                              hipStream_t stream) {
  const float* base = (const float*)d_in[0];
  const float* src  = (const float*)d_in[1];
  const int*   sub  = (const int*)d_in[2];
  const float* W    = (const float*)d_in[3];
  float* out = (float*)d_out;

  short* Wp  = (short*)d_ws;                       // 1 MB
  short* Wtp = Wp  + EMBED * KSEL;                 // 1 MB
  short* Tp  = Wtp + EMBED * KSEL;                 // 2 MB
  char*  rest = (char*)(Tp + BATCH * KSEL);        // offset 4 MB

  pack_w_kernel<<<EMBED * KSEL / 256, 256, 0, stream>>>(W, sub, Wp, Wtp);

  const size_t need_f32 = (size_t)4 * 1024 * 1024 +
                          (size_t)NSLICE * BATCH * KSEL * sizeof(float);
  if (ws_size >= need_f32) {
    float* Tpart = (float*)rest;                   // 32 MB
    gemm1a_kernel<float><<<512, 512, 0, stream>>>(base, src, Wp, Tpart);
    reduce_kernel<float><<<BATCH * 16 / 512, 512, 0, stream>>>(Tpart, Tp);
  } else {
    short* Tpart = (short*)rest;                   // 8 MB
    gemm1a_kernel<short><<<512, 512, 0, stream>>>(base, src, Wp, Tpart);
    reduce_kernel<short><<<BATCH * 16 / 512, 512, 0, stream>>>(Tpart, Tp);
  }

  gemm2_kernel<<<(BATCH / 64) * 16, 256, 0, stream>>>(base, Tp, Wtp, out);
}

// Round 6
// 129.413 us; speedup vs baseline: 1.1023x; 1.1023x over previous
//
#include <hip/hip_runtime.h>
#include <hip/hip_bf16.h>

typedef __attribute__((ext_vector_type(4))) float  f32x4;
typedef __attribute__((ext_vector_type(8))) short  short8;
typedef unsigned int u32;

#define EMBED 4096
#define LR    512
#define KSEL  128
#define BATCH 8192
#define NSLICE 8
#define KSLICE 512

__device__ __forceinline__ short f2bf(float x) {
  union { float f; unsigned u; } c; c.f = x;
  unsigned r = c.u + 0x7FFFu + ((c.u >> 16) & 1u);  // RNE
  return (short)(r >> 16);
}
__device__ __forceinline__ float bf2f(short s) {
  union { unsigned u; float f; } c; c.u = ((unsigned)(unsigned short)s) << 16;
  return c.f;
}
__device__ __forceinline__ void storept(float* p, float v) { *p = v; }
__device__ __forceinline__ void storept(short* p, float v) { *p = f2bf(v); }
__device__ __forceinline__ void loadpart(const float* p, f32x4& a, f32x4& b) {
  a += *(const f32x4*)p; b += *(const f32x4*)(p + 4);
}
__device__ __forceinline__ void loadpart(const short* p, f32x4& a, f32x4& b) {
  short8 v = *(const short8*)p;
  #pragma unroll
  for (int j = 0; j < 4; ++j) { a[j] += bf2f(v[j]); b[j] += bf2f(v[4 + j]); }
}
__device__ __forceinline__ void gload16(const void* g, void* l) {
  __builtin_amdgcn_global_load_lds((const __attribute__((address_space(1))) u32*)g,
                                   (__attribute__((address_space(3))) u32*)l, 16, 0, 0);
}

// K0: gather selected columns of W, emit two bf16 MFMA-packed layouts.
// Wp : [e/8][128 cols][8]  (B-operand for GEMM1: kk-dim = embed)
// Wtp: [c/8][4096 e ][8]  (B-operand for GEMM2: kk-dim = sel index)
__global__ __launch_bounds__(256) void pack_w_kernel(
    const float* __restrict__ W, const int* __restrict__ sel,
    short* __restrict__ Wp, short* __restrict__ Wtp) {
  int idx = blockIdx.x * 256 + threadIdx.x;
  int e = idx >> 7;
  int c = idx & 127;
  int r = sel[c];
  short v = f2bf(W[e * LR + r]);
  Wp [(((e >> 3) << 7) + c) * 8 + (e & 7)] = v;
  Wtp[(((c >> 3) << 12) + e) * 8 + (c & 7)] = v;
}

// K1a: Tpart[slice] = (src-base)[:, k0:k0+512) @ Wsel[k0:k0+512), :]
// m97-invariant: ALL global reads via global_load_lds; compute phase is
// pure LDS + MFMA. 1024 blocks = 128 row-tiles(M=64) x 8 kslices; 256 thr
// = 4 waves (2M x 2N: wave covers 32 rows x 64 cols). BK=32, 16 steps,
// double-buffered 24KB/buf: A_base 8KB | A_src 8KB | B 8KB.
// A LDS slot (row, c) holds global 16B-chunk c^(row&7)  (XOR swizzle via
// pre-swizzled SOURCE address; LDS dest stays linear for gload_lds).
// B = linear copy of Wp slice (already MFMA-packed).
template<typename PT>
__global__ __launch_bounds__(256, 4) void gemm1a_kernel(
    const float* __restrict__ base, const float* __restrict__ src,
    const short* __restrict__ Wp, PT* __restrict__ Tpart) {
  __shared__ __align__(16) char smem[49152];   // 2 bufs x 24KB
  const int t  = threadIdx.x;
  const int w  = t >> 6, l = t & 63;
  const int lr = l & 15, lg = l >> 4;
  const int wm = w >> 1, wn = w & 1;
  const int slice = blockIdx.x & 7, tile = blockIdx.x >> 3;
  const int row0 = tile * 64;
  const int k0 = slice * KSLICE;

  // staging addresses (q0 = t, q1 = t + 256; chunk = 16B = 4 f32)
  const int r_q0 = t >> 3,          c_q0 = t & 7;
  const int r_q1 = (t + 256) >> 3,  c_q1 = t & 7;
  const size_t aoff0 = (size_t)(row0 + r_q0) * EMBED + k0 + ((c_q0 ^ (r_q0 & 7)) << 2);
  const size_t aoff1 = (size_t)(row0 + r_q1) * EMBED + k0 + ((c_q1 ^ (r_q1 & 7)) << 2);
  const short* bsrc = Wp + ((size_t)(k0 >> 3) * 128 + t) * 8;

  #define STAGE(s, b) do {                                              \
    char* d_ = smem + (b) * 24576 + t * 16;                             \
    gload16(base + aoff0 + (s) * 32, d_);                               \
    gload16(base + aoff1 + (s) * 32, d_ + 4096);                        \
    gload16(src  + aoff0 + (s) * 32, d_ + 8192);                        \
    gload16(src  + aoff1 + (s) * 32, d_ + 12288);                       \
    gload16(bsrc + (s) * 4096,        d_ + 16384);                      \
    gload16(bsrc + (s) * 4096 + 2048, d_ + 20480);                      \
  } while (0)

  f32x4 acc[2][4];
  #pragma unroll
  for (int m = 0; m < 2; ++m)
    #pragma unroll
    for (int n = 0; n < 4; ++n) acc[m][n] = (f32x4){0.f, 0.f, 0.f, 0.f};

  // compute-side LDS byte offsets (A chunks XOR-swizzled)
  const int row_m0 = wm * 32 + lr;          // m=0 row
  const int row_m1 = wm * 32 + 16 + lr;     // m=1 row
  const int a00 = row_m0 * 128 + (((lg << 1))     ^ (row_m0 & 7)) * 16;
  const int a01 = row_m0 * 128 + (((lg << 1) | 1) ^ (row_m0 & 7)) * 16;
  const int a10 = row_m1 * 128 + (((lg << 1))     ^ (row_m1 & 7)) * 16;
  const int a11 = row_m1 * 128 + (((lg << 1) | 1) ^ (row_m1 & 7)) * 16;
  const int bofs = 16384 + (lg * 128 + wn * 64 + lr) * 16;

  STAGE(0, 0);
  int b = 0;
  for (int s = 0; s < 16; ++s) {
    __syncthreads();                        // buf b staged; prev readers done
    if (s < 15) STAGE(s + 1, b ^ 1);        // flies under this step's compute
    const char* tb = smem + b * 24576;

    short8 ua[2];
    #pragma unroll
    for (int m = 0; m < 2; ++m) {
      const int o0 = m ? a10 : a00, o1 = m ? a11 : a01;
      f32x4 b0 = *(const f32x4*)(tb + o0);
      f32x4 b1 = *(const f32x4*)(tb + o1);
      f32x4 s0 = *(const f32x4*)(tb + 8192 + o0);
      f32x4 s1 = *(const f32x4*)(tb + 8192 + o1);
      union { short8 v; __hip_bfloat162 h[4]; } u;
      u.h[0] = __float22bfloat162_rn(make_float2(s0[0] - b0[0], s0[1] - b0[1]));
      u.h[1] = __float22bfloat162_rn(make_float2(s0[2] - b0[2], s0[3] - b0[3]));
      u.h[2] = __float22bfloat162_rn(make_float2(s1[0] - b1[0], s1[1] - b1[1]));
      u.h[3] = __float22bfloat162_rn(make_float2(s1[2] - b1[2], s1[3] - b1[3]));
      ua[m] = u.v;
    }
    #pragma unroll
    for (int n = 0; n < 4; ++n) {
      short8 bf = *(const short8*)(tb + bofs + n * 256);
      acc[0][n] = __builtin_amdgcn_mfma_f32_16x16x32_bf16(ua[0], bf, acc[0][n], 0, 0, 0);
      acc[1][n] = __builtin_amdgcn_mfma_f32_16x16x32_bf16(ua[1], bf, acc[1][n], 0, 0, 0);
    }
    b ^= 1;
  }
  #undef STAGE

  // lane holds Tpart[slice][row0 + wm*32 + m*16 + lg*4 + r][wn*64 + n*16 + lr]
  PT* o = Tpart + ((size_t)slice * BATCH + row0 + wm * 32 + lg * 4) * KSEL + wn * 64 + lr;
  #pragma unroll
  for (int m = 0; m < 2; ++m)
    #pragma unroll
    for (int n = 0; n < 4; ++n)
      #pragma unroll
      for (int r = 0; r < 4; ++r)
        storept(o + ((size_t)m * 16 + r) * KSEL + n * 16, acc[m][n][r]);
}

// K1b: Tp (packed bf16 [kk/8][8192][8]) = sum of 8 Tpart slices
template<typename PT>
__global__ __launch_bounds__(512) void reduce_kernel(
    const PT* __restrict__ Tpart, short* __restrict__ Tp) {
  const int tid = blockIdx.x * 512 + threadIdx.x;   // 0..131071
  const int kkg = tid & 15, row = tid >> 4;
  f32x4 s0 = {0.f, 0.f, 0.f, 0.f}, s1 = {0.f, 0.f, 0.f, 0.f};
  #pragma unroll
  for (int s = 0; s < NSLICE; ++s)
    loadpart(Tpart + ((size_t)s * BATCH + row) * KSEL + kkg * 8, s0, s1);
  short8 o;
  #pragma unroll
  for (int j = 0; j < 4; ++j) { o[j] = f2bf(s0[j]); o[4 + j] = f2bf(s1[j]); }
  *(short8*)(Tp + ((size_t)kkg * BATCH + row) * 8) = o;
}

// K2: out = base + T @ Wsel^T. Block: 64 rows x 256 cols, 4 waves.
__global__ __launch_bounds__(256) void gemm2_kernel(
    const float* __restrict__ base, const short* __restrict__ Tp,
    const short* __restrict__ Wtp, float* __restrict__ out) {
  const int t  = threadIdx.x;
  const int w  = t >> 6, l = t & 63;
  const int lr = l & 15, lg = l >> 4;
  const int mt = blockIdx.x >> 4, nt = blockIdx.x & 15;
  const int row0 = mt * 64;
  const int col0 = nt * 256 + w * 64;

  short8 afr[4][4];
  #pragma unroll
  for (int m = 0; m < 4; ++m)
    #pragma unroll
    for (int ks = 0; ks < 4; ++ks)
      afr[m][ks] = *(const short8*)(Tp + (size_t)(((ks * 4 + lg) << 13) + row0 + m * 16 + lr) * 8);

  f32x4 acc[4][4];
  #pragma unroll
  for (int m = 0; m < 4; ++m)
    #pragma unroll
    for (int nf = 0; nf < 4; ++nf) acc[m][nf] = (f32x4){0.f, 0.f, 0.f, 0.f};

  #pragma unroll
  for (int nf = 0; nf < 4; ++nf) {
    short8 bfr[4];
    #pragma unroll
    for (int ks = 0; ks < 4; ++ks)
      bfr[ks] = *(const short8*)(Wtp + (size_t)(((ks * 4 + lg) << 12) + col0 + nf * 16 + lr) * 8);
    #pragma unroll
    for (int m = 0; m < 4; ++m)
      #pragma unroll
      for (int ks = 0; ks < 4; ++ks)
        acc[m][nf] = __builtin_amdgcn_mfma_f32_16x16x32_bf16(afr[m][ks], bfr[ks], acc[m][nf], 0, 0, 0);
  }

  #pragma unroll
  for (int m = 0; m < 4; ++m)
    #pragma unroll
    for (int r = 0; r < 4; ++r) {
      const size_t row = row0 + m * 16 + lg * 4 + r;
      #pragma unroll
      for (int nf = 0; nf < 4; ++nf) {
        const size_t o = row * EMBED + col0 + nf * 16 + lr;
        out[o] = base[o] + acc[m][nf][r];
      }
    }
}

extern "C" void kernel_launch(void* const* d_in, const int* in_sizes, int n_in,
                              void* d_out, int out_size, void* d_ws, size_t ws_size,
                              hipStream_t stream) {
  const float* base = (const float*)d_in[0];
  const float* src  = (const float*)d_in[1];
  const int*   sub  = (const int*)d_in[2];
  const float* W    = (const float*)d_in[3];
  float* out = (float*)d_out;

  short* Wp  = (short*)d_ws;                       // 1 MB
  short* Wtp = Wp  + EMBED * KSEL;                 // 1 MB
  short* Tp  = Wtp + EMBED * KSEL;                 // 2 MB
  char*  rest = (char*)(Tp + BATCH * KSEL);        // offset 4 MB

  pack_w_kernel<<<EMBED * KSEL / 256, 256, 0, stream>>>(W, sub, Wp, Wtp);

  const size_t need_f32 = (size_t)4 * 1024 * 1024 +
                          (size_t)NSLICE * BATCH * KSEL * sizeof(float);
  if (ws_size >= need_f32) {
    float* Tpart = (float*)rest;                   // 32 MB
    gemm1a_kernel<float><<<1024, 256, 0, stream>>>(base, src, Wp, Tpart);
    reduce_kernel<float><<<BATCH * 16 / 512, 512, 0, stream>>>(Tpart, Tp);
  } else {
    short* Tpart = (short*)rest;                   // 8 MB
    gemm1a_kernel<short><<<1024, 256, 0, stream>>>(base, src, Wp, Tpart);
    reduce_kernel<short><<<BATCH * 16 / 512, 512, 0, stream>>>(Tpart, Tp);
  }

  gemm2_kernel<<<(BATCH / 64) * 16, 256, 0, stream>>>(base, Tp, Wtp, out);
}